// Round 6
// baseline (980.173 us; speedup 1.0000x reference)
//
#include <hip/hip_runtime.h>
#include <stdint.h>

// Problem constants
#define NN    50000
#define EE    800000
#define IN_C  128
#define ED_C  64
#define HID_C 256
#define BB    128
#define KK    1000
#define G1_C  128
#define NV    50176            // NN padded to 196*256 for scan
#define CHUNK 204800           // edge slots per proj chunk (multiple of 128 & 256)
#define SL    256              // slots per scatadd block

// Dtype model (R1/R2 forensics): fp32 inputs, int32 indices, fp32 outputs.
// R5 post-mortem: k_edge2 latency-bound (nothing >20% busy); gemm family
// ~430us unchanged by LDS staging (too-thin compute between barriers).
// R6: (1) fused row-local MLP chain (h0->h1->h2->g1->gate in LDS),
//     (2) chunked two-phase edge stage with 128-slot/thread run-merge.

typedef __attribute__((ext_vector_type(8))) short bfrag;   // 8 x bf16
typedef __attribute__((ext_vector_type(4))) float f4acc;   // 4 x f32 acc

__device__ __forceinline__ unsigned short f2bs(float f){   // f32 -> bf16 (RNE)
  unsigned u = __float_as_uint(f);
  return (unsigned short)((u + 0x7fffu + ((u >> 16) & 1u)) >> 16);
}
__device__ __forceinline__ float bs2f(unsigned short s){
  return __uint_as_float(((unsigned)s) << 16);
}

__device__ __forceinline__ void atomicMaxFloat(float* addr, float val){
  int old = __float_as_int(*addr);
  while (__int_as_float(old) < val){
    int assumed = old;
    old = atomicCAS((int*)addr, assumed, __float_as_int(val));
    if (old == assumed) break;
  }
}

// ---------------- prep: cast+transpose weights to bf16 (Wt[n][k] = W[k][n]) --
__global__ __launch_bounds__(256) void k_prep(
    const float* __restrict__ We, const float* __restrict__ W1,
    const float* __restrict__ W2, const float* __restrict__ Wg1,
    unsigned short* __restrict__ Wet, unsigned short* __restrict__ W1t,
    unsigned short* __restrict__ W2t, unsigned short* __restrict__ Wg1t)
{
  int i = blockIdx.x * 256 + threadIdx.x;
  if (i < 128 * 64){ int c = i >> 6, k = i & 63;  Wet[i]  = f2bs(We[k * 128 + c]); }
  if (i < 256 * 128){ int n = i >> 7, k = i & 127; W1t[i]  = f2bs(W1[k * 256 + n]); }
  if (i < 256 * 256){ int n = i >> 8, k = i & 255; W2t[i]  = f2bs(W2[k * 256 + n]); }
  if (i < 128 * 256){ int n = i >> 8, k = i & 255; Wg1t[i] = f2bs(Wg1[k * 128 + n]); }
}

// ---------------- init: zero agg/cnt/fill/aux/denom/pooled, gmax=-1e30 ----
__global__ __launch_bounds__(256) void k_init(float* __restrict__ agg,
                                              int* __restrict__ cnt,
                                              int* __restrict__ fill,
                                              int* __restrict__ aux,
                                              float* __restrict__ gmax,
                                              float* __restrict__ denom,
                                              float* __restrict__ pooled){
  size_t i = (size_t)blockIdx.x * 256 + threadIdx.x;
  if (i < (size_t)NN * IN_C) agg[i] = 0.f;
  if (i < NV){ cnt[i] = 0; fill[i] = 0; }
  if (i < 256) aux[i] = 0;
  if (i < BB){ gmax[i] = -1e30f; denom[i] = 0.f; }
  if (i < BB * HID_C) pooled[i] = 0.f;
}

// ---------------- counting sort by dst: hist -> scan -> scatter ----------
__global__ __launch_bounds__(256) void k_hist(const int* __restrict__ ei,
                                              int* __restrict__ cnt){
  int e = blockIdx.x * 256 + threadIdx.x;
  if (e < EE) atomicAdd(&cnt[ei[EE + e]], 1);
}

__global__ __launch_bounds__(256) void k_scan1(const int* __restrict__ cnt,
                                               int* __restrict__ off,
                                               int* __restrict__ aux){
  __shared__ int s[256];
  int t = threadIdx.x, i = blockIdx.x * 256 + t;
  int val = cnt[i];
  s[t] = val; __syncthreads();
#pragma unroll
  for (int o = 1; o < 256; o <<= 1){
    int v = (t >= o) ? s[t - o] : 0;
    __syncthreads();
    s[t] += v;
    __syncthreads();
  }
  off[i] = s[t] - val;
  if (t == 255) aux[blockIdx.x] = s[255];
}

__global__ __launch_bounds__(256) void k_scan2(int* __restrict__ aux){
  __shared__ int s[256];
  int t = threadIdx.x;
  int val = aux[t];
  s[t] = val; __syncthreads();
#pragma unroll
  for (int o = 1; o < 256; o <<= 1){
    int v = (t >= o) ? s[t - o] : 0;
    __syncthreads();
    s[t] += v;
    __syncthreads();
  }
  aux[t] = s[t] - val;
}

__global__ __launch_bounds__(256) void k_scan3(int* __restrict__ off,
                                               const int* __restrict__ aux){
  int i = blockIdx.x * 256 + threadIdx.x;
  off[i] += aux[blockIdx.x];
}

__global__ __launch_bounds__(256) void k_scatter(const int* __restrict__ ei,
                                                 const int* __restrict__ off,
                                                 int* __restrict__ fill,
                                                 uint4* __restrict__ sorted){
  int e = blockIdx.x * 256 + threadIdx.x;
  if (e < EE){
    int s = ei[e], d = ei[EE + e];
    int pos = off[d] + atomicAdd(&fill[d], 1);
    sorted[pos] = make_uint4((unsigned)e, (unsigned)s, (unsigned)d, 0u);
  }
}

// ---------------- edge phase A: proj[slot] = ea[eid]@We + be (bf16 out) ---
// Block = 256 thr / 4 waves; tile = 128 sorted slots x 128 channels.
__global__ __launch_bounds__(256) void k_eproj(
    const uint4* __restrict__ sorted, const float* __restrict__ edge_attr,
    const unsigned short* __restrict__ Wet, const float* __restrict__ be,
    unsigned short* __restrict__ proj, int base)
{
  __shared__ unsigned short eaS[128 * 72];
  __shared__ int eidS[128];
  const int tid = threadIdx.x;
  const int s0 = base + blockIdx.x * 128;          // global slot base
  if (tid < 128) eidS[tid] = (int)sorted[s0 + tid].x;
  __syncthreads();
#pragma unroll
  for (int t = 0; t < 8; ++t){
    int f4 = t * 256 + tid;
    int er = f4 >> 4;
    int kk = (f4 & 15) * 4;
    const float4 v = *(const float4*)(edge_attr + (size_t)eidS[er] * ED_C + kk);
    unsigned p0 = (unsigned)f2bs(v.x) | ((unsigned)f2bs(v.y) << 16);
    unsigned p1 = (unsigned)f2bs(v.z) | ((unsigned)f2bs(v.w) << 16);
    *(uint2*)&eaS[er * 72 + kk] = make_uint2(p0, p1);
  }
  __syncthreads();

  const int lane = tid & 63, wv = tid >> 6;
  const int q = lane >> 4, l15 = lane & 15;

  f4acc acc[2][8];
  const f4acc zz = {0.f, 0.f, 0.f, 0.f};
#pragma unroll
  for (int mt = 0; mt < 2; ++mt)
#pragma unroll
    for (int nt = 0; nt < 8; ++nt) acc[mt][nt] = zz;

#pragma unroll
  for (int ks = 0; ks < 2; ++ks){
    bfrag a[2], b[8];
#pragma unroll
    for (int mt = 0; mt < 2; ++mt){
      int m = wv * 32 + mt * 16 + l15;
      a[mt] = *(const bfrag*)&eaS[m * 72 + ks * 32 + q * 8];
    }
#pragma unroll
    for (int nt = 0; nt < 8; ++nt){
      int c = nt * 16 + l15;
      b[nt] = *(const bfrag*)(Wet + c * ED_C + ks * 32 + q * 8);
    }
#pragma unroll
    for (int mt = 0; mt < 2; ++mt)
#pragma unroll
      for (int nt = 0; nt < 8; ++nt)
        acc[mt][nt] = __builtin_amdgcn_mfma_f32_16x16x32_bf16(a[mt], b[nt], acc[mt][nt], 0, 0, 0);
  }

  float bev[8];
#pragma unroll
  for (int nt = 0; nt < 8; ++nt) bev[nt] = be[nt * 16 + l15];

  unsigned short* pout = proj + (size_t)blockIdx.x * 128 * 128;  // chunk-local
#pragma unroll
  for (int mt = 0; mt < 2; ++mt){
#pragma unroll
    for (int r = 0; r < 4; ++r){
      int m = wv * 32 + mt * 16 + q * 4 + r;
#pragma unroll
      for (int nt = 0; nt < 8; ++nt){
        int c = nt * 16 + l15;
        pout[(size_t)m * 128 + c] = f2bs(acc[mt][nt][r] + bev[nt]);
      }
    }
  }
}

// ---------------- edge phase B: agg[dst] += relu(x[src] + proj) ----------
// Thread owns one channel over SL/2=128 consecutive sorted slots; run-merge
// over equal dst -> ~1 atomic per 16 slots per channel.
__global__ __launch_bounds__(256) void k_scatadd(
    const uint4* __restrict__ sorted, const unsigned short* __restrict__ proj,
    const float* __restrict__ x, float* __restrict__ agg, int base)
{
  __shared__ int sd[SL], ss[SL];
  const int tid = threadIdx.x;
  const int s0 = blockIdx.x * SL;                  // chunk-local
  int gs = base + s0 + tid;
  if (gs < EE){ uint4 v = sorted[gs]; ss[tid] = (int)v.y; sd[tid] = (int)v.z; }
  else sd[tid] = -1;
  __syncthreads();
  const int c = tid & 127, half = tid >> 7;
  const int lo = half * (SL / 2), hi = lo + SL / 2;
  float run = 0.f; int dcur = -1;
  for (int s = lo; s < hi; ++s){
    int d = sd[s];
    if (d != dcur){
      if (dcur >= 0) atomicAdd(&agg[(size_t)dcur * IN_C + c], run);
      run = 0.f; dcur = d;
    }
    if (d >= 0){
      float m = x[(size_t)ss[s] * IN_C + c] + bs2f(proj[(size_t)(s0 + s) * 128 + c]);
      run += (m > 0.f ? m : 0.f);
    }
  }
  if (dcur >= 0) atomicAdd(&agg[(size_t)dcur * IN_C + c], run);
}

// ---------------- fused MLP: h0=agg+x -> h1 -> h2 -> g1 -> gate ----------
// 32-row tile lives in LDS end-to-end; B-frags from L2-hot transposed weights.
__global__ __launch_bounds__(256, 2) void k_mlp(
    const float* __restrict__ agg, const float* __restrict__ x,
    const unsigned short* __restrict__ W1t, const float* __restrict__ b1,
    const unsigned short* __restrict__ W2t, const float* __restrict__ b2,
    const unsigned short* __restrict__ Wg1t, const float* __restrict__ bg1,
    const float* __restrict__ Wg2, const float* __restrict__ bg2,
    unsigned short* __restrict__ h2b, float* __restrict__ gate)
{
  __shared__ unsigned short h0S[32 * 136];   // reused as g1S in phase 3/4
  __shared__ unsigned short h1S[32 * 264];
  __shared__ unsigned short h2S[32 * 264];
  const int tid = threadIdx.x, lane = tid & 63, wv = tid >> 6;
  const int q = lane >> 4, l15 = lane & 15;
  const int r0 = blockIdx.x * 32;
  const f4acc zz = {0.f, 0.f, 0.f, 0.f};

  // stage h0 = agg + x (bf16)
#pragma unroll
  for (int i = 0; i < 16; ++i){
    int idx = i * 256 + tid;                  // 4096 elems
    int row = idx >> 7, col = idx & 127;
    int gr = r0 + row; if (gr >= NN) gr = NN - 1;
    h0S[row * 136 + col] = f2bs(agg[(size_t)gr * IN_C + col] + x[(size_t)gr * IN_C + col]);
  }
  __syncthreads();

  // phase 1: h1 = relu(h0 @ W1 + b1); wave covers n in [wv*64, wv*64+64)
  {
    f4acc acc[2][4];
#pragma unroll
    for (int mt = 0; mt < 2; ++mt)
#pragma unroll
      for (int nt = 0; nt < 4; ++nt) acc[mt][nt] = zz;
#pragma unroll
    for (int ks = 0; ks < 4; ++ks){
      bfrag a[2], b[4];
#pragma unroll
      for (int mt = 0; mt < 2; ++mt)
        a[mt] = *(const bfrag*)&h0S[(mt * 16 + l15) * 136 + ks * 32 + q * 8];
#pragma unroll
      for (int nt = 0; nt < 4; ++nt){
        int n = wv * 64 + nt * 16 + l15;
        b[nt] = *(const bfrag*)(W1t + n * 128 + ks * 32 + q * 8);
      }
#pragma unroll
      for (int mt = 0; mt < 2; ++mt)
#pragma unroll
        for (int nt = 0; nt < 4; ++nt)
          acc[mt][nt] = __builtin_amdgcn_mfma_f32_16x16x32_bf16(a[mt], b[nt], acc[mt][nt], 0, 0, 0);
    }
#pragma unroll
    for (int nt = 0; nt < 4; ++nt){
      int n = wv * 64 + nt * 16 + l15;
      float bv = b1[n];
#pragma unroll
      for (int mt = 0; mt < 2; ++mt)
#pragma unroll
        for (int r = 0; r < 4; ++r){
          int m = mt * 16 + q * 4 + r;
          float v = acc[mt][nt][r] + bv;
          h1S[m * 264 + n] = f2bs(v > 0.f ? v : 0.f);
        }
    }
  }
  __syncthreads();

  // phase 2: h2 = h1 @ W2 + b2 -> h2S (+ global h2b below)
  {
    f4acc acc[2][4];
#pragma unroll
    for (int mt = 0; mt < 2; ++mt)
#pragma unroll
      for (int nt = 0; nt < 4; ++nt) acc[mt][nt] = zz;
#pragma unroll
    for (int ks = 0; ks < 8; ++ks){
      bfrag a[2], b[4];
#pragma unroll
      for (int mt = 0; mt < 2; ++mt)
        a[mt] = *(const bfrag*)&h1S[(mt * 16 + l15) * 264 + ks * 32 + q * 8];
#pragma unroll
      for (int nt = 0; nt < 4; ++nt){
        int n = wv * 64 + nt * 16 + l15;
        b[nt] = *(const bfrag*)(W2t + n * 256 + ks * 32 + q * 8);
      }
#pragma unroll
      for (int mt = 0; mt < 2; ++mt)
#pragma unroll
        for (int nt = 0; nt < 4; ++nt)
          acc[mt][nt] = __builtin_amdgcn_mfma_f32_16x16x32_bf16(a[mt], b[nt], acc[mt][nt], 0, 0, 0);
    }
#pragma unroll
    for (int nt = 0; nt < 4; ++nt){
      int n = wv * 64 + nt * 16 + l15;
      float bv = b2[n];
#pragma unroll
      for (int mt = 0; mt < 2; ++mt)
#pragma unroll
        for (int r = 0; r < 4; ++r){
          int m = mt * 16 + q * 4 + r;
          h2S[m * 264 + n] = f2bs(acc[mt][nt][r] + bv);
        }
    }
  }
  __syncthreads();

  // coalesced h2 -> global (uint4), while phase 3 inputs are ready
#pragma unroll
  for (int i = 0; i < 4; ++i){
    int idx = i * 256 + tid;                  // 1024 uint4
    int row = idx >> 5, chk = idx & 31;
    uint4 v = *(const uint4*)&h2S[row * 264 + chk * 8];
    int gr = r0 + row;
    if (gr < NN) *(uint4*)(h2b + (size_t)gr * HID_C + chk * 8) = v;
  }

  // phase 3: g1 = relu(h2 @ Wg1 + bg1) -> g1S(=h0S); wave covers 32 n
  {
    f4acc acc[2][2];
#pragma unroll
    for (int mt = 0; mt < 2; ++mt)
#pragma unroll
      for (int nt = 0; nt < 2; ++nt) acc[mt][nt] = zz;
#pragma unroll
    for (int ks = 0; ks < 8; ++ks){
      bfrag a[2], b[2];
#pragma unroll
      for (int mt = 0; mt < 2; ++mt)
        a[mt] = *(const bfrag*)&h2S[(mt * 16 + l15) * 264 + ks * 32 + q * 8];
#pragma unroll
      for (int nt = 0; nt < 2; ++nt){
        int n = wv * 32 + nt * 16 + l15;
        b[nt] = *(const bfrag*)(Wg1t + n * 256 + ks * 32 + q * 8);
      }
#pragma unroll
      for (int mt = 0; mt < 2; ++mt)
#pragma unroll
        for (int nt = 0; nt < 2; ++nt)
          acc[mt][nt] = __builtin_amdgcn_mfma_f32_16x16x32_bf16(a[mt], b[nt], acc[mt][nt], 0, 0, 0);
    }
    __syncthreads();   // h0S no longer needed as h0
#pragma unroll
    for (int nt = 0; nt < 2; ++nt){
      int n = wv * 32 + nt * 16 + l15;
      float bv = bg1[n];
#pragma unroll
      for (int mt = 0; mt < 2; ++mt)
#pragma unroll
        for (int r = 0; r < 4; ++r){
          int m = mt * 16 + q * 4 + r;
          float v = acc[mt][nt][r] + bv;
          h0S[m * 136 + n] = f2bs(v > 0.f ? v : 0.f);
        }
    }
  }
  __syncthreads();

  // phase 4: gate[r] = g1[r,:128] . Wg2 + bg2 (8 threads per row)
  {
    int row = tid >> 3, j = tid & 7;
    float p = 0.f;
#pragma unroll
    for (int i = 0; i < 16; ++i){
      int cc = j * 16 + i;
      p += bs2f(h0S[row * 136 + cc]) * Wg2[cc];
    }
    p += __shfl_down(p, 4, 8);
    p += __shfl_down(p, 2, 8);
    p += __shfl_down(p, 1, 8);
    int gr = r0 + row;
    if (j == 0 && gr < NN) gate[gr] = p + bg2[0];
  }
}

// ---------------- segment max (batch sorted; block pre-reduce) ----------
__global__ __launch_bounds__(256) void k_gmax(const float* __restrict__ gate,
                                              const int* __restrict__ batch,
                                              float* __restrict__ gmax, int nrows){
  __shared__ float red[256];
  const int tid = threadIdx.x;
  const int n0 = blockIdx.x * 256;
  const int n = n0 + tid;
  const int nlast = (n0 + 255 < nrows) ? n0 + 255 : nrows - 1;
  const int bmin = batch[n0], bmax = batch[nlast];
  float val = -3e38f; int b = bmax;
  if (n < nrows){ b = batch[n]; val = gate[n]; }
  for (int bb = bmin; bb <= bmax; ++bb){
    red[tid] = (b == bb) ? val : -3e38f;
    __syncthreads();
    for (int s = 128; s > 0; s >>= 1){
      if (tid < s) red[tid] = fmaxf(red[tid], red[tid + s]);
      __syncthreads();
    }
    if (tid == 0 && red[0] > -1e37f) atomicMaxFloat(&gmax[bb], red[0]);
    __syncthreads();
  }
}

// ---------------- a = exp(gate - gmax[b]); denom[b] += a ----------------
__global__ __launch_bounds__(256) void k_expsum(const float* __restrict__ gate,
                                                const int* __restrict__ batch,
                                                const float* __restrict__ gmax,
                                                float* __restrict__ aexp,
                                                float* __restrict__ denom, int nrows){
  __shared__ float red[256];
  const int tid = threadIdx.x;
  const int n0 = blockIdx.x * 256;
  const int n = n0 + tid;
  const int nlast = (n0 + 255 < nrows) ? n0 + 255 : nrows - 1;
  const int bmin = batch[n0], bmax = batch[nlast];
  float val = 0.f; int b = bmax;
  if (n < nrows){
    b = batch[n];
    val = expf(gate[n] - gmax[b]);
    aexp[n] = val;
  }
  for (int bb = bmin; bb <= bmax; ++bb){
    red[tid] = (b == bb) ? val : 0.f;
    __syncthreads();
    for (int s = 128; s > 0; s >>= 1){
      if (tid < s) red[tid] += red[tid + s];
      __syncthreads();
    }
    if (tid == 0 && red[0] != 0.f) atomicAdd(&denom[bb], red[0]);
    __syncthreads();
  }
}

// ---------------- pooled[b] += (a/denom[b]) * h2[n] ----------------
__global__ __launch_bounds__(256) void k_pool(const unsigned short* __restrict__ h2b,
                                              const float* __restrict__ aexp,
                                              const float* __restrict__ denom,
                                              const int* __restrict__ batch,
                                              float* __restrict__ pooled, int nrows){
  const int c = threadIdx.x;
  const int n0 = blockIdx.x * 256;
  int n1 = n0 + 256; if (n1 > nrows) n1 = nrows;
  float acc = 0.f;
  int curb = batch[n0];
  for (int n = n0; n < n1; ++n){
    int b = batch[n];
    if (b != curb){
      atomicAdd(&pooled[(size_t)curb * HID_C + c], acc);
      acc = 0.f; curb = b;
    }
    float wgt = aexp[n] / denom[b];
    acc = fmaf(wgt, bs2f(h2b[(size_t)n * HID_C + c]), acc);
  }
  atomicAdd(&pooled[(size_t)curb * HID_C + c], acc);
}

// ---------------- head: logits = pooled @ Wh + bh ----------------
__global__ __launch_bounds__(256) void k_head(const float* __restrict__ pooled,
                                              const float* __restrict__ Wh,
                                              const float* __restrict__ bh,
                                              float* __restrict__ out_logits,
                                              float* __restrict__ out_pooled){
  __shared__ float p[HID_C];
  const int b = blockIdx.x, t = threadIdx.x;
  float pv = pooled[(size_t)b * HID_C + t];
  p[t] = pv;
  out_pooled[(size_t)b * HID_C + t] = pv;
  __syncthreads();
  for (int c = t; c < KK; c += 256){
    float acc = bh[c];
#pragma unroll 8
    for (int k = 0; k < HID_C; ++k)
      acc = fmaf(p[k], Wh[k * KK + c], acc);
    out_logits[(size_t)b * KK + c] = acc;
  }
}

extern "C" void kernel_launch(void* const* d_in, const int* in_sizes, int n_in,
                              void* d_out, int out_size, void* d_ws, size_t ws_size,
                              hipStream_t stream) {
  const float* x   = (const float*)d_in[0];
  const int*   ei  = (const int*)d_in[1];
  const float* ea  = (const float*)d_in[2];
  const int*   batch = (const int*)d_in[3];
  const float* We  = (const float*)d_in[4];
  const float* be  = (const float*)d_in[5];
  const float* W1  = (const float*)d_in[6];
  const float* b1  = (const float*)d_in[7];
  const float* W2  = (const float*)d_in[8];
  const float* b2  = (const float*)d_in[9];
  const float* Wg1 = (const float*)d_in[10];
  const float* bg1 = (const float*)d_in[11];
  const float* Wg2 = (const float*)d_in[12];
  const float* bg2 = (const float*)d_in[13];
  const float* Wh  = (const float*)d_in[14];
  const float* bh  = (const float*)d_in[15];

  float* out_logits = (float*)d_out;
  float* out_pooled = out_logits + (size_t)BB * KK;

  // ws layout (~92 MB, matches R5 footprint):
  //   agg | small f32 | weights | sorted | R:(projb chunk; aliased by h2b and
  //   by cnt/off/fill — all disjoint in time)
  float* agg    = (float*)d_ws;                       // N*128 f32
  float* gate   = agg   + (size_t)NN * IN_C;          // N
  float* aexp   = gate  + NN;                         // N
  float* gmax   = aexp  + NN;                         // B
  float* denom  = gmax  + BB;                         // B
  float* pooled = denom + BB;                         // B*256
  unsigned short* Wet  = (unsigned short*)(pooled + (size_t)BB * HID_C);
  unsigned short* W1t  = Wet + 128 * 64;
  unsigned short* W2t  = W1t + 256 * 128;
  unsigned short* Wg1t = W2t + 256 * 256;
  uint4* sorted = (uint4*)(Wg1t + 128 * 256);         // EE * 16B (12.8 MB)
  unsigned short* projb = (unsigned short*)(sorted + EE);  // CHUNK*128 bf16 (52.4 MB)
  unsigned short* h2b   = projb;                      // alias: projb dead before k_mlp
  int* cnt  = (int*)projb;                            // alias: dead before k_eproj
  int* off  = cnt + NV;
  int* fill = off + NV;
  int* aux  = fill + NV;

  k_prep<<<256, 256, 0, stream>>>(We, W1, W2, Wg1, Wet, W1t, W2t, Wg1t);
  k_init<<<(NN * IN_C + 255) / 256, 256, 0, stream>>>(agg, cnt, fill, aux, gmax, denom, pooled);
  // counting sort by dst
  k_hist   <<<(EE + 255) / 256, 256, 0, stream>>>(ei, cnt);
  k_scan1  <<<NV / 256, 256, 0, stream>>>(cnt, off, aux);
  k_scan2  <<<1, 256, 0, stream>>>(aux);
  k_scan3  <<<NV / 256, 256, 0, stream>>>(off, aux);
  k_scatter<<<(EE + 255) / 256, 256, 0, stream>>>(ei, off, fill, sorted);
  // chunked two-phase edge stage (cnt/off/fill dead; projb live per chunk)
  for (int base = 0; base < EE; base += CHUNK){
    int ns = (EE - base < CHUNK) ? (EE - base) : CHUNK;
    k_eproj  <<<ns / 128, 256, 0, stream>>>(sorted, ea, Wet, be, projb, base);
    k_scatadd<<<ns / SL,  256, 0, stream>>>(sorted, projb, x, agg, base);
  }
  // fused per-node MLP chain (projb dead; h2b aliases it)
  k_mlp<<<(NN + 31) / 32, 256, 0, stream>>>(agg, x, W1t, b1, W2t, b2,
                                            Wg1t, bg1, Wg2, bg2, h2b, gate);
  // segment softmax + attention pooling + head
  k_gmax  <<<(NN + 255) / 256, 256, 0, stream>>>(gate, batch, gmax, NN);
  k_expsum<<<(NN + 255) / 256, 256, 0, stream>>>(gate, batch, gmax, aexp, denom, NN);
  k_pool  <<<(NN + 255) / 256, 256, 0, stream>>>(h2b, aexp, denom, batch, pooled, NN);
  k_head<<<BB, 256, 0, stream>>>(pooled, Wh, bh, out_logits, out_pooled);
}